// Round 4
// baseline (210.712 us; speedup 1.0000x reference)
//
#include <hip/hip_runtime.h>

// KnowledgeEmbedding loss via bf16 MFMA GEMM.
// R15: relation-fusion / gather-dedup attack. R0/R13/R14 falsified occupancy,
// bank conflicts, atomics, and coalescing -- but all kept scattered-row volume
// constant at 16 gathers/batch-row (only 9 unique: rel0,1 share user head;
// rel2-7 share product head; rel1,2 share word pos-tail; rel0 pos-tail ==
// product head). This version: one block = 16 batch rows x ALL 8 relations.
// Unique entities (user,product,word) staged fp32 in LDS once; per relation:
// A=bf16(h+rvec) materialized from LDS, negs restaged (L2-hot, 53KB), MFMA
// 16x256, pos dots read h (and rel0/1/2 tails) from LDS. 8 unique scattered
// gathers/row (u,p,w,b,c,rp5,rp6,rp7) -- 2x fewer than R14.
// Numerics identical to R14: fp32 LDS copy exact, same bf16 rounding points,
// bias folded at k=100 (A=bias, B=1.0), zero-B k-tail trick.
// Grid 256 x 256thr, LDS 76KB (1 block/CU resident; occupancy proven moot).

#define EMBED   100
#define BATCH   4096
#define NUM_NEG 256
#define PF      100   // floats per fp32 LDS entity row (400 B, float4-aligned)
#define PITCH   104   // shorts per bf16 LDS row (208 B, odd-mod-32 dwords)

typedef __attribute__((ext_vector_type(8))) short s8;
typedef __attribute__((ext_vector_type(4))) short s4v;
typedef __attribute__((ext_vector_type(4))) float f4;

struct RelP {
    const float* tail;
    const float* bias;
    int tc;
};

struct Params {
    RelP rel[8];
    const float* user;
    const float* prod;
    const float* rel_vecs;
    const int*   batch_idxs;
    const int*   neg_idxs;
    float*       out;
};

__device__ __forceinline__ float softplus_f(float x) {
    float e = __expf(-fabsf(x));
    return fmaxf(x, 0.0f) + __logf(1.0f + e);
}

__device__ __forceinline__ unsigned short bf16_rne(float f) {
    unsigned u = __float_as_uint(f);
    u += 0x7FFFu + ((u >> 16) & 1u);
    return (unsigned short)(u >> 16);
}

__device__ __forceinline__ float bf16_to_f(short s) {
    return __uint_as_float(((unsigned)(unsigned short)s) << 16);
}

__device__ __forceinline__ s4v pack4(float4 f) {
    s4v v = { (short)bf16_rne(f.x), (short)bf16_rne(f.y),
              (short)bf16_rne(f.z), (short)bf16_rne(f.w) };
    return v;
}

__launch_bounds__(256, 1)
__global__ void ke_kernel(Params p) {
    // grid: 256 blocks; block b owns batch rows 16b..16b+15, all 8 relations.
    const int bid = blockIdx.x;
    const int R0  = bid * 16;
    const int tid = threadIdx.x;

    __shared__ __align__(16) float U[16 * PF];      // 6400 B  (user heads)
    __shared__ __align__(16) float P[16 * PF];      // 6400 B  (product rows)
    __shared__ __align__(16) float W[16 * PF];      // 6400 B  (word pos-tails)
    __shared__ __align__(16) short Ac[16 * PITCH];  // 3328 B  (bf16 h+rvec)
    __shared__ __align__(16) short Bs[NUM_NEG * PITCH]; // 53248 B (bf16 negs)
    __shared__ float wsum[4];

    const int row  = tid >> 4;           // 0..15 (batch row within block)
    const int j    = tid & 15;           // 0..15 (lane within row group)
    const int grow = R0 + row;

    // ---- stage unique entity rows (fp32, exact copy): u, p, w ----
    {
        const int c0 = p.batch_idxs[grow * 8 + 0];
        const float4* s = (const float4*)(p.user + (size_t)c0 * EMBED);
        float4* d = (float4*)(U + row * PF);
        d[j] = s[j];
        if (j < 9) d[j + 16] = s[j + 16];
    }
    {
        const int c1 = p.batch_idxs[grow * 8 + 1];
        const float4* s = (const float4*)(p.prod + (size_t)c1 * EMBED);
        float4* d = (float4*)(P + row * PF);
        d[j] = s[j];
        if (j < 9) d[j + 16] = s[j + 16];
    }
    {
        const int c2 = p.batch_idxs[grow * 8 + 2];
        const float4* s = (const float4*)(p.rel[1].tail + (size_t)c2 * EMBED);
        float4* d = (float4*)(W + row * PF);
        d[j] = s[j];
        if (j < 9) d[j + 16] = s[j + 16];
    }

    __syncthreads();

    const int g    = tid & 7;            // B-staging lane (0..7)
    const int rloc = tid >> 3;           // B-staging row slot (0..31)
    const int wave = tid >> 6;
    const int lane = tid & 63;
    const int li   = lane & 15;
    const int q    = lane >> 4;

    float local = 0.0f;

#pragma unroll
    for (int r = 0; r < 8; ++r) {
        const RelP rp = p.rel[r];
        const float* hrow = (r < 2 ? U : P) + row * PF;
        const float* rv   = p.rel_vecs + r * EMBED;

        // ---- A_cur: bf16(h + rvec), bias at k=100 ----
        {
            short* dst = Ac + row * PITCH;
            {
                float4 f = *(const float4*)(hrow + 4 * j);
                const float4 a = *(const float4*)(rv + 4 * j);
                f.x += a.x; f.y += a.y; f.z += a.z; f.w += a.w;
                *(s4v*)(dst + 4 * j) = pack4(f);
            }
            if (j < 9) {
                const int c = j + 16;    // 16..24
                float4 f = *(const float4*)(hrow + 4 * c);
                const float4 a = *(const float4*)(rv + 4 * c);
                f.x += a.x; f.y += a.y; f.z += a.z; f.w += a.w;
                *(s4v*)(dst + 4 * c) = pack4(f);
            }
            if (j == 15) {               // bias at shorts 100..103
                const int ti = p.batch_idxs[grow * 8 + rp.tc];
                s4v v = { (short)bf16_rne(rp.bias[ti]), 0, 0, 0 };
                *(s4v*)(dst + 100) = v;
            }
        }

        // ---- Bs: 256 neg rows, 8 passes, 8 lanes/row (L2-hot) ----
#pragma unroll
        for (int pass = 0; pass < 8; ++pass) {
            const int brow = pass * 32 + rloc;
            const int n = p.neg_idxs[r * NUM_NEG + brow];
            const float* s = rp.tail + (size_t)n * EMBED;
            short* dst = Bs + brow * PITCH;
#pragma unroll
            for (int t = 0; t < 3; ++t) {
                const int c = g + 8 * t; // 0..23
                *(s4v*)(dst + 4 * c) = pack4(*(const float4*)(s + 4 * c));
            }
            if (g == 0) {                // floats 96..99 + 1.0@k=100
                float4 f = *(const float4*)(s + 96);
                s8 v = { (short)bf16_rne(f.x), (short)bf16_rne(f.y),
                         (short)bf16_rne(f.z), (short)bf16_rne(f.w),
                         (short)0x3F80, 0, 0, 0 };
                *(s8*)(dst + 96) = v;
            }
        }

        __syncthreads();

        // ---- MFMA: 4 waves, each 16 rows x 64 negs ----
        f4 acc[4];
#pragma unroll
        for (int jj = 0; jj < 4; ++jj) acc[jj] = (f4){0.f, 0.f, 0.f, 0.f};

        const short* Ab = Ac + li * PITCH;
        const short* Bb = Bs + (wave * 64 + li) * PITCH;

#pragma unroll
        for (int s2 = 0; s2 < 3; ++s2) { // k = 0..95
            const int co = 8 * (q + 4 * s2);
            const s8 a = *(const s8*)(Ab + co);
#pragma unroll
            for (int jj = 0; jj < 4; ++jj) {
                const s8 b = *(const s8*)(Bb + jj * 16 * PITCH + co);
                acc[jj] = __builtin_amdgcn_mfma_f32_16x16x32_bf16(a, b, acc[jj], 0, 0, 0);
            }
        }
        {   // k-tail: only q==0 (chunk 12) real; zero B for q>=1
            const s8 z = {0, 0, 0, 0, 0, 0, 0, 0};
            const s8 a = *(const s8*)(Ab + 96);
#pragma unroll
            for (int jj = 0; jj < 4; ++jj) {
                s8 b = *(const s8*)(Bb + jj * 16 * PITCH + 96);
                b = q ? z : b;
                acc[jj] = __builtin_amdgcn_mfma_f32_16x16x32_bf16(a, b, acc[jj], 0, 0, 0);
            }
        }

#pragma unroll
        for (int jj = 0; jj < 4; ++jj) {
            local += softplus_f(acc[jj].x);
            local += softplus_f(acc[jj].y);
            local += softplus_f(acc[jj].z);
            local += softplus_f(acc[jj].w);
        }

        // ---- positive term: 16 lanes/row; t from LDS (r<=2) or global ----
        {
            const int ti = p.batch_idxs[grow * 8 + rp.tc];
            const short* exr = Ac + row * PITCH;
            const float* tsrc = (r == 0) ? (P + row * PF)
                              : (r <= 2) ? (W + row * PF)
                              : (rp.tail + (size_t)ti * EMBED);
            float d0 = 0.f, d1 = 0.f, d2 = 0.f, d3 = 0.f;
            {
                const s4v e = *(const s4v*)(exr + 4 * j);
                const float4 t0 = *(const float4*)(tsrc + 4 * j);
                d0 = fmaf(bf16_to_f(e.x), t0.x, d0);
                d1 = fmaf(bf16_to_f(e.y), t0.y, d1);
                d2 = fmaf(bf16_to_f(e.z), t0.z, d2);
                d3 = fmaf(bf16_to_f(e.w), t0.w, d3);
            }
            if (j < 9) {
                const int c = j + 16;
                const s4v e = *(const s4v*)(exr + 4 * c);
                const float4 t0 = *(const float4*)(tsrc + 4 * c);
                d0 = fmaf(bf16_to_f(e.x), t0.x, d0);
                d1 = fmaf(bf16_to_f(e.y), t0.y, d1);
                d2 = fmaf(bf16_to_f(e.z), t0.z, d2);
                d3 = fmaf(bf16_to_f(e.w), t0.w, d3);
            }
            float d = (d0 + d1) + (d2 + d3);
            d += __shfl_xor(d, 1, 64);
            d += __shfl_xor(d, 2, 64);
            d += __shfl_xor(d, 4, 64);
            d += __shfl_xor(d, 8, 64);   // 16-lane group holds full dot
            if (j == 0) local += softplus_f(-(d + rp.bias[ti]));
        }

        __syncthreads();                 // Ac/Bs reads done before next iter
    }

    // ---- reduction ----
#pragma unroll
    for (int off = 32; off > 0; off >>= 1)
        local += __shfl_down(local, off, 64);

    if (lane == 0) wsum[wave] = local;
    __syncthreads();
    if (tid == 0) {
        const float s = (wsum[0] + wsum[1]) + (wsum[2] + wsum[3]);
        atomicAdd(p.out, s * (1.0f / BATCH));
    }
}

extern "C" void kernel_launch(void* const* d_in, const int* in_sizes, int n_in,
                              void* d_out, int out_size, void* d_ws, size_t ws_size,
                              hipStream_t stream) {
    const float* user  = (const float*)d_in[0];
    const float* prod  = (const float*)d_in[1];
    const float* word  = (const float*)d_in[2];
    const float* brand = (const float*)d_in[3];
    const float* cat   = (const float*)d_in[4];
    const float* rprod = (const float*)d_in[5];

    Params p;
    p.user       = user;
    p.prod       = prod;
    p.rel_vecs   = (const float*)d_in[6];
    p.batch_idxs = (const int*)d_in[15];
    p.neg_idxs   = (const int*)d_in[16];
    p.out        = (float*)d_out;

    p.rel[0] = {prod,  (const float*)d_in[7],  1};  // purchase
    p.rel[1] = {word,  (const float*)d_in[8],  2};  // mentions
    p.rel[2] = {word,  (const float*)d_in[9],  2};  // describe
    p.rel[3] = {brand, (const float*)d_in[10], 3};  // produced
    p.rel[4] = {cat,   (const float*)d_in[11], 4};  // belongs
    p.rel[5] = {rprod, (const float*)d_in[12], 5};  // also_bought
    p.rel[6] = {rprod, (const float*)d_in[13], 6};  // also_viewed
    p.rel[7] = {rprod, (const float*)d_in[14], 7};  // together

    hipMemsetAsync(d_out, 0, sizeof(float), stream);
    ke_kernel<<<256, 256, 0, stream>>>(p);
}

// Round 5
// 152.388 us; speedup vs baseline: 1.3827x; 1.3827x over previous
//
#include <hip/hip_runtime.h>

// KnowledgeEmbedding loss via bf16 MFMA GEMM, single phase.
// R16 = revert to R14 (best known: 40 us kernel / 152 us e2e).
// Session falsification matrix: occupancy (R13 flat), LDS conflicts (R13),
// atomics (R13), coalescing+dedup (R14 flat), fetch-volume dedup via relation
// fusion (R15: 2.3x WORSE -- serialized the gather MLP that carries the
// kernel). Conclusion: kernel is bound by the memory system's random-access
// service rate on ~15 MB of unique scattered 400B row-gathers (~400 GB/s,
// reproduced by three structurally different kernels); concurrency must stay
// maximal (512 independent blocks), volume is algorithmically irreducible.
//  - 8 lanes per row staging: 8-lane group reads one contiguous 128B line.
//  - BN=256: each head row gathered exactly once; grid 512 = 8 rel x 64 rb.
//  - XCD-affine rel = bid&7 (neg tables L2-resident per XCD).
//  - PITCH=104 (odd-mod-32 dwords, conflict-free), bias folded at k=100
//    (A=bias, B=1.0), zero-B k-tail for k=104..127.

#define EMBED   100
#define BATCH   4096
#define NUM_NEG 256
#define BM      64
#define BN      256
#define PITCH   104   // shorts per row = 208 B = 52 dwords (odd mod 32 banks)

typedef __attribute__((ext_vector_type(8))) short s8;
typedef __attribute__((ext_vector_type(4))) short s4;
typedef __attribute__((ext_vector_type(4))) float f4;

struct RelP {
    const float* head;
    const float* tail;
    const float* bias;
    int hc, tc;
};

struct Params {
    RelP rel[8];
    const float* rel_vecs;
    const int*   batch_idxs;
    const int*   neg_idxs;
    float*       out;
};

__device__ __forceinline__ float softplus_f(float x) {
    float e = __expf(-fabsf(x));
    return fmaxf(x, 0.0f) + __logf(1.0f + e);
}

__device__ __forceinline__ unsigned short bf16_rne(float f) {
    unsigned u = __float_as_uint(f);
    u += 0x7FFFu + ((u >> 16) & 1u);
    return (unsigned short)(u >> 16);
}

__device__ __forceinline__ float bf16_to_f(short s) {
    return __uint_as_float(((unsigned)(unsigned short)s) << 16);
}

__device__ __forceinline__ s4 pack4(float4 f) {
    s4 v = { (short)bf16_rne(f.x), (short)bf16_rne(f.y),
             (short)bf16_rne(f.z), (short)bf16_rne(f.w) };
    return v;
}

__launch_bounds__(256, 2)
__global__ void ke_kernel(Params p) {
    // grid: 512. bid&7 = rel (XCD-affine under %8 round-robin dispatch).
    const int bid = blockIdx.x;
    const int r   = bid & 7;
    const int rb  = bid >> 3;            // rowblock 0..63 (64 rows each)
    const int tid = threadIdx.x;

    __shared__ __align__(16) short As[BM * PITCH];   // 13312 B
    __shared__ __align__(16) short Bs[BN * PITCH];   // 53248 B -> total 66560 B

    const RelP rp = p.rel[r];

    const int g    = tid & 7;            // lane within row-group (0..7)
    const int rloc = tid >> 3;           // row slot within pass (0..31)

    // ---- A staging: 64 rows, 2 passes, 8 lanes/row (coalesced 128B/group) ----
    const float4* rv4 = (const float4*)(p.rel_vecs + r * EMBED);
#pragma unroll
    for (int pass = 0; pass < 2; ++pass) {
        const int row  = pass * 32 + rloc;
        const int grow = rb * BM + row;
        const int h = p.batch_idxs[grow * 8 + rp.hc];
        const float4* s4p = (const float4*)(rp.head + (size_t)h * EMBED);
        short* dst = As + row * PITCH;
#pragma unroll
        for (int t = 0; t < 3; ++t) {
            const int j = g + 8 * t;     // 0..23
            float4 f = s4p[j];
            const float4 a = rv4[j];
            f.x += a.x; f.y += a.y; f.z += a.z; f.w += a.w;
            *(s4*)(dst + 4 * j) = pack4(f);
        }
        if (g == 0) {                    // floats 96..99 + bias@100 + zeros
            const int ti = p.batch_idxs[grow * 8 + rp.tc];
            const unsigned short extra = bf16_rne(rp.bias[ti]);
            float4 f = s4p[24];
            const float4 a = rv4[24];
            f.x += a.x; f.y += a.y; f.z += a.z; f.w += a.w;
            s8 v = { (short)bf16_rne(f.x), (short)bf16_rne(f.y),
                     (short)bf16_rne(f.z), (short)bf16_rne(f.w),
                     (short)extra, 0, 0, 0 };
            *(s8*)(dst + 96) = v;
        }
    }

    // ---- B staging: 256 rows, 8 passes, 8 lanes/row ----
#pragma unroll
    for (int pass = 0; pass < 8; ++pass) {
        const int row = pass * 32 + rloc;
        const int n = p.neg_idxs[r * NUM_NEG + row];
        const float4* s4p = (const float4*)(rp.tail + (size_t)n * EMBED);
        short* dst = Bs + row * PITCH;
#pragma unroll
        for (int t = 0; t < 3; ++t) {
            const int j = g + 8 * t;
            *(s4*)(dst + 4 * j) = pack4(s4p[j]);
        }
        if (g == 0) {                    // floats 96..99 + 1.0@100 (bias pass)
            float4 f = s4p[24];
            s8 v = { (short)bf16_rne(f.x), (short)bf16_rne(f.y),
                     (short)bf16_rne(f.z), (short)bf16_rne(f.w),
                     (short)0x3F80, 0, 0, 0 };
            *(s8*)(dst + 96) = v;
        }
    }

    // pos-term prep (issued before barrier): 4 threads/row, 64 rows
    const int prow_l = tid >> 2;         // 0..63
    const int pp     = tid & 3;
    const int pgrow  = rb * BM + prow_l;
    const int pt     = p.batch_idxs[pgrow * 8 + rp.tc];
    const float* ptail = rp.tail + (size_t)pt * EMBED;
    const float  pbias = rp.bias[pt];

    __syncthreads();

    // ---- MFMA: 4 waves as 2x2, wave tile 32 rows x 128 negs ----
    const int wave = tid >> 6;
    const int lane = tid & 63;
    const int li   = lane & 15;
    const int q    = lane >> 4;
    const int wm   = wave >> 1;          // row half (32 rows)
    const int wn   = wave & 1;           // neg half (128 negs)

    f4 acc[2][8];
#pragma unroll
    for (int i = 0; i < 2; ++i)
#pragma unroll
        for (int j = 0; j < 8; ++j)
            acc[i][j] = (f4){0.f, 0.f, 0.f, 0.f};

    const short* Ab = As + (wm * 32 + li) * PITCH;
    const short* Bb = Bs + (wn * 128 + li) * PITCH;

#pragma unroll
    for (int s = 0; s < 3; ++s) {        // k = 0..95, chunks q+4s all real
        const int co = 8 * (q + 4 * s);
        s8 a[2], b[8];
        a[0] = *(const s8*)(Ab + co);
        a[1] = *(const s8*)(Ab + 16 * PITCH + co);
#pragma unroll
        for (int j = 0; j < 8; ++j)
            b[j] = *(const s8*)(Bb + j * 16 * PITCH + co);
#pragma unroll
        for (int i = 0; i < 2; ++i)
#pragma unroll
            for (int j = 0; j < 8; ++j)
                acc[i][j] = __builtin_amdgcn_mfma_f32_16x16x32_bf16(a[i], b[j], acc[i][j], 0, 0, 0);
    }
    {   // s=3: k=96..127. Only q==0 (chunk 12) real; zero B for q>=1 so the
        // garbage A broadcast contributes exactly 0.
        const s8 z = {0, 0, 0, 0, 0, 0, 0, 0};
        s8 a[2], b[8];
        a[0] = *(const s8*)(Ab + 96);
        a[1] = *(const s8*)(Ab + 16 * PITCH + 96);
#pragma unroll
        for (int j = 0; j < 8; ++j) {
            b[j] = *(const s8*)(Bb + j * 16 * PITCH + 96);
            b[j] = q ? z : b[j];
        }
#pragma unroll
        for (int i = 0; i < 2; ++i)
#pragma unroll
            for (int j = 0; j < 8; ++j)
                acc[i][j] = __builtin_amdgcn_mfma_f32_16x16x32_bf16(a[i], b[j], acc[i][j], 0, 0, 0);
    }

    // ---- epilogue: softplus-sum (bias folded into acc, layout-agnostic) ----
    float local = 0.0f;
#pragma unroll
    for (int i = 0; i < 2; ++i)
#pragma unroll
        for (int j = 0; j < 8; ++j) {
            local += softplus_f(acc[i][j].x);
            local += softplus_f(acc[i][j].y);
            local += softplus_f(acc[i][j].z);
            local += softplus_f(acc[i][j].w);
        }

    // ---- positive term: 4 lanes/row, lane p reads float4 j = p+4t (coalesced) ----
    {
        const short* exr = As + prow_l * PITCH;
        const float4* tv = (const float4*)ptail;
        float d0 = 0.f, d1 = 0.f, d2 = 0.f, d3 = 0.f;
#pragma unroll
        for (int t = 0; t < 6; ++t) {
            const int j = pp + 4 * t;    // 0..23
            const s4 e = *(const s4*)(exr + 4 * j);
            const float4 t0 = tv[j];
            d0 = fmaf(bf16_to_f(e.x), t0.x, d0);
            d1 = fmaf(bf16_to_f(e.y), t0.y, d1);
            d2 = fmaf(bf16_to_f(e.z), t0.z, d2);
            d3 = fmaf(bf16_to_f(e.w), t0.w, d3);
        }
        if (pp == 0) {                   // j=24: floats 96..99
            const s4 e = *(const s4*)(exr + 96);
            const float4 t0 = tv[24];
            d0 = fmaf(bf16_to_f(e.x), t0.x, d0);
            d1 = fmaf(bf16_to_f(e.y), t0.y, d1);
            d2 = fmaf(bf16_to_f(e.z), t0.z, d2);
            d3 = fmaf(bf16_to_f(e.w), t0.w, d3);
        }
        float d = (d0 + d1) + (d2 + d3);
        d += __shfl_xor(d, 1, 64);
        d += __shfl_xor(d, 2, 64);       // 4-lane group holds full dot
        if (pp == 0) local += softplus_f(-(d + pbias));
    }

    // ---- reduction ----
#pragma unroll
    for (int off = 32; off > 0; off >>= 1)
        local += __shfl_down(local, off, 64);

    __syncthreads();                     // all As/Bs reads done -> safe to alias
    float* wsum = (float*)Bs;
    if ((tid & 63) == 0) wsum[tid >> 6] = local;
    __syncthreads();
    if (tid == 0) {
        const float s = (wsum[0] + wsum[1]) + (wsum[2] + wsum[3]);
        atomicAdd(p.out, s * (1.0f / BATCH));
    }
}

extern "C" void kernel_launch(void* const* d_in, const int* in_sizes, int n_in,
                              void* d_out, int out_size, void* d_ws, size_t ws_size,
                              hipStream_t stream) {
    const float* user  = (const float*)d_in[0];
    const float* prod  = (const float*)d_in[1];
    const float* word  = (const float*)d_in[2];
    const float* brand = (const float*)d_in[3];
    const float* cat   = (const float*)d_in[4];
    const float* rprod = (const float*)d_in[5];

    Params p;
    p.rel_vecs   = (const float*)d_in[6];
    p.batch_idxs = (const int*)d_in[15];
    p.neg_idxs   = (const int*)d_in[16];
    p.out        = (float*)d_out;

    p.rel[0] = {user, prod,  (const float*)d_in[7],  0, 1};  // purchase
    p.rel[1] = {user, word,  (const float*)d_in[8],  0, 2};  // mentions
    p.rel[2] = {prod, word,  (const float*)d_in[9],  1, 2};  // describe
    p.rel[3] = {prod, brand, (const float*)d_in[10], 1, 3};  // produced
    p.rel[4] = {prod, cat,   (const float*)d_in[11], 1, 4};  // belongs
    p.rel[5] = {prod, rprod, (const float*)d_in[12], 1, 5};  // also_bought
    p.rel[6] = {prod, rprod, (const float*)d_in[13], 1, 6};  // also_viewed
    p.rel[7] = {prod, rprod, (const float*)d_in[14], 1, 7};  // together

    hipMemsetAsync(d_out, 0, sizeof(float), stream);
    ke_kernel<<<512, 256, 0, stream>>>(p);
}